// Round 3
// baseline (598.073 us; speedup 1.0000x reference)
//
#include <hip/hip_runtime.h>
#include <hip/hip_bf16.h>
#include <stdint.h>

// Problem constants
//   x:[32,2048,512] fp32  W*:[512,512] fp32  b*:[512] fp32  factor:[1,64,256,8] fp32
//   Output fp32 [32,2048,512].
//   Internally: cast x,W to bf16; q/k/v proj via bf16 MFMA; Q/K/V staged bf16.
//   per (b,a): slice = rows [b*2048+a*32, +32) x 512 of Q/K/V
//     k2[h][r] = sum_lr K[..,lr] * f[a,lr,r]; same for v2
//     scores[lr][r] = sum_h q[..][lr] * k2[h][r] / 8 ; softmax over r (8)
//     out[row, lr*64+h-ish] = sum_r p[r]*v2[h][r]   (fp32 out)

typedef unsigned short ushort_t;

using bf16x8 = __attribute__((ext_vector_type(8))) short;   // 8 bf16 (4 VGPRs)
using f32x4  = __attribute__((ext_vector_type(4))) float;   // MFMA acc

__device__ __forceinline__ float bf2f(unsigned short u) {
  union { unsigned int i; float f; } v;
  v.i = ((unsigned int)u) << 16;
  return v.f;
}
__device__ __forceinline__ unsigned short f2bf(float f) {
  __hip_bfloat16 h = __float2bfloat16(f);  // round-to-nearest-even
  return *reinterpret_cast<unsigned short*>(&h);
}

// async global->LDS, 16B per lane. LDS dest = wave-uniform base + lane*16.
__device__ __forceinline__ void load_lds16(const void* g, void* l) {
  __builtin_amdgcn_global_load_lds(
      (const __attribute__((address_space(1))) unsigned int*)g,
      (__attribute__((address_space(3))) unsigned int*)l,
      16, 0, 0);
}

// ---------------------------------------------------------------------------
// Kernel 0: fp32 -> bf16 cast, 4 elems/thread.
// ---------------------------------------------------------------------------
__global__ __launch_bounds__(256)
void cast_f32_bf16(const float* __restrict__ src, ushort_t* __restrict__ dst,
                   int n4) {
  int i = blockIdx.x * blockDim.x + threadIdx.x;
  if (i < n4) {
    float4 v = ((const float4*)src)[i];
    ushort_t p[4] = {f2bf(v.x), f2bf(v.y), f2bf(v.z), f2bf(v.w)};
    *(uint2*)(dst + 4 * (size_t)i) = *(const uint2*)p;
  }
}

// ---------------------------------------------------------------------------
// Kernel 1: C[M=65536, N=512] = X[M,512] @ W[N,512]^T + bias, bf16 MFMA.
// grid = (N/128, M/128, 3); block = 256 (4 waves). BK=32, m97 2-barrier loop.
// X, W are bf16 (pre-cast in ws); bias fp32; output bf16 (staged).
// ---------------------------------------------------------------------------
__global__ __launch_bounds__(256)
void gemm_qkv(const ushort_t* __restrict__ X,
              const ushort_t* __restrict__ W0, const float* __restrict__ B0,
              const ushort_t* __restrict__ W1, const float* __restrict__ B1,
              const ushort_t* __restrict__ W2, const float* __restrict__ B2,
              ushort_t* __restrict__ Qo, ushort_t* __restrict__ Ko,
              ushort_t* __restrict__ Vo) {
  __shared__ __align__(16) short sA[128 * 32];  // [row][k] row-major, no pad
  __shared__ __align__(16) short sB[128 * 32];

  const ushort_t* W;
  const float* Bi;
  ushort_t* O;
  if (blockIdx.z == 0)      { W = W0; Bi = B0; O = Qo; }
  else if (blockIdx.z == 1) { W = W1; Bi = B1; O = Ko; }
  else                      { W = W2; Bi = B2; O = Vo; }

  const int tid  = threadIdx.x;
  const int lane = tid & 63;
  const int wid  = tid >> 6;
  const int m0 = blockIdx.y * 128;
  const int n0 = blockIdx.x * 128;
  const int wave_m = (wid & 1) * 64;
  const int wave_n = (wid >> 1) * 64;
  const int quad = lane >> 4;
  const int l15  = lane & 15;

  f32x4 acc[4][4];
#pragma unroll
  for (int i = 0; i < 4; ++i)
#pragma unroll
    for (int j = 0; j < 4; ++j) acc[i][j] = f32x4{0.f, 0.f, 0.f, 0.f};

  // staging segments: 512 segs of 16B per tile; wave w covers [w*128, +128)
  const int s0 = wid * 128 + lane;
  const int s1 = s0 + 64;
  short* ldsA0 = &sA[(wid * 128) * 8];
  short* ldsA1 = &sA[(wid * 128 + 64) * 8];
  short* ldsB0 = &sB[(wid * 128) * 8];
  short* ldsB1 = &sB[(wid * 128 + 64) * 8];

  for (int kt = 0; kt < 512; kt += 32) {
    const ushort_t* ga0 = X + ((size_t)(m0 + (s0 >> 2)) << 9) + kt + (s0 & 3) * 8;
    const ushort_t* ga1 = X + ((size_t)(m0 + (s1 >> 2)) << 9) + kt + (s1 & 3) * 8;
    const ushort_t* gb0 = W + ((size_t)(n0 + (s0 >> 2)) << 9) + kt + (s0 & 3) * 8;
    const ushort_t* gb1 = W + ((size_t)(n0 + (s1 >> 2)) << 9) + kt + (s1 & 3) * 8;
    load_lds16(ga0, ldsA0);
    load_lds16(ga1, ldsA1);
    load_lds16(gb0, ldsB0);
    load_lds16(gb1, ldsB1);
    __syncthreads();  // drains vmcnt(0) -> LDS tiles valid

    bf16x8 af[4], bfr[4];
#pragma unroll
    for (int i = 0; i < 4; ++i)
      af[i] = *(const bf16x8*)&sA[(wave_m + i * 16 + l15) * 32 + quad * 8];
#pragma unroll
    for (int j = 0; j < 4; ++j)
      bfr[j] = *(const bf16x8*)&sB[(wave_n + j * 16 + l15) * 32 + quad * 8];
#pragma unroll
    for (int i = 0; i < 4; ++i)
#pragma unroll
      for (int j = 0; j < 4; ++j)
        acc[i][j] = __builtin_amdgcn_mfma_f32_16x16x32_bf16(af[i], bfr[j],
                                                            acc[i][j], 0, 0, 0);
    __syncthreads();  // all waves done reading before next stage overwrites
  }

  // epilogue: C/D layout col=lane&15, row=(lane>>4)*4+reg  [verified m89/m91]
#pragma unroll
  for (int j = 0; j < 4; ++j) {
    const int gn = n0 + wave_n + j * 16 + l15;
    const float bv = Bi[gn];
#pragma unroll
    for (int i = 0; i < 4; ++i) {
      const int gmBase = m0 + wave_m + i * 16 + quad * 4;
      f32x4 c = acc[i][j];
#pragma unroll
      for (int rg = 0; rg < 4; ++rg) {
        O[((size_t)(gmBase + rg) << 9) + gn] = f2bf(c[rg] + bv);
      }
    }
  }
}

// ---------------------------------------------------------------------------
// Kernel 2: per (b,a) block: k2/v2 = factor contraction, scores, softmax, PV.
// grid = (64, 32); block = 256. Q/K/V bf16; factor fp32; out fp32.
// ---------------------------------------------------------------------------
__global__ __launch_bounds__(256)
void attn_bc(const ushort_t* __restrict__ Q, const ushort_t* __restrict__ K,
             const ushort_t* __restrict__ V, const float* __restrict__ F,
             float* __restrict__ Out) {
  const int a = blockIdx.x;  // 0..63
  const int b = blockIdx.y;  // 0..31
  const int t = threadIdx.x; // 0..255

  __shared__ float k2[64][8];
  __shared__ float v2[64][8];

  // Phase 1: k2[h][r] = sum_lr K[b, a*32+h/2, (h&1)*256+lr] * f[a][lr][r]
  // thread t: h = t>>2, lr-chunk c = t&3 (64 lr each); reduce over 4 lanes.
  {
    const int h = t >> 2;
    const int c = t & 3;
    const size_t rowoff =
        ((size_t)(b * 2048 + a * 32 + (h >> 1)) << 9) + (h & 1) * 256;
    const ushort_t* Kp = K + rowoff + c * 64;
    const ushort_t* Vp = V + rowoff + c * 64;
    const float* Fp = F + (size_t)a * 2048 + (size_t)(c * 64) * 8;

    float accK[8], accV[8];
#pragma unroll
    for (int r = 0; r < 8; ++r) { accK[r] = 0.f; accV[r] = 0.f; }

    for (int u = 0; u < 64; u += 8) {
      uint4 kraw = *(const uint4*)(Kp + u);
      uint4 vraw = *(const uint4*)(Vp + u);
      const unsigned short* ks = (const unsigned short*)&kraw;
      const unsigned short* vs = (const unsigned short*)&vraw;
#pragma unroll
      for (int j = 0; j < 8; ++j) {
        const float kv = bf2f(ks[j]);
        const float vv = bf2f(vs[j]);
        float fr[8];
        *(float4*)&fr[0] = *(const float4*)(Fp + (size_t)(u + j) * 8);
        *(float4*)&fr[4] = *(const float4*)(Fp + (size_t)(u + j) * 8 + 4);
#pragma unroll
        for (int r = 0; r < 8; ++r) {
          accK[r] += kv * fr[r];
          accV[r] += vv * fr[r];
        }
      }
    }
    // reduce across the 4 chunk-lanes (t^1, t^2 within same wave)
#pragma unroll
    for (int r = 0; r < 8; ++r) {
      accK[r] += __shfl_xor(accK[r], 1);
      accK[r] += __shfl_xor(accK[r], 2);
      accV[r] += __shfl_xor(accV[r], 1);
      accV[r] += __shfl_xor(accV[r], 2);
    }
    if (c == 0) {
#pragma unroll
      for (int r = 0; r < 8; ++r) {
        k2[h][r] = accK[r];
        v2[h][r] = accV[r];
      }
    }
  }
  __syncthreads();

  // Phase 2: thread t = lr in [0,256)
  {
    const int lr = t;
    float s[8];
#pragma unroll
    for (int r = 0; r < 8; ++r) s[r] = 0.f;

    const size_t qbase = ((size_t)(b * 2048 + a * 32)) << 9;
    for (int h = 0; h < 64; ++h) {
      const float qv = bf2f(Q[qbase + ((size_t)(h >> 1) << 9) + (h & 1) * 256 + lr]);
#pragma unroll
      for (int r = 0; r < 8; ++r) s[r] += qv * k2[h][r];
    }

    // scale by 1/sqrt(64), softmax over r
    float mx = -1e30f;
#pragma unroll
    for (int r = 0; r < 8; ++r) { s[r] *= 0.125f; mx = fmaxf(mx, s[r]); }
    float sum = 0.f;
#pragma unroll
    for (int r = 0; r < 8; ++r) { s[r] = __expf(s[r] - mx); sum += s[r]; }
    const float inv = 1.0f / sum;
#pragma unroll
    for (int r = 0; r < 8; ++r) s[r] *= inv;

    // out row l = b*2048 + a*32 + lr/8, col base (lr&7)*64, 64 contiguous h
    const size_t obase =
        (((size_t)(b * 2048 + a * 32 + (lr >> 3))) << 9) + (lr & 7) * 64;
    for (int h0 = 0; h0 < 64; h0 += 4) {
      float4 o;
      float* op = (float*)&o;
#pragma unroll
      for (int j = 0; j < 4; ++j) {
        const int h = h0 + j;
        float v = 0.f;
#pragma unroll
        for (int r = 0; r < 8; ++r) v += s[r] * v2[h][r];
        op[j] = v;
      }
      *(float4*)(Out + obase + h0) = o;
    }
  }
}

// ---------------------------------------------------------------------------
extern "C" void kernel_launch(void* const* d_in, const int* in_sizes, int n_in,
                              void* d_out, int out_size, void* d_ws,
                              size_t ws_size, hipStream_t stream) {
  const float* x  = (const float*)d_in[0];
  const float* Wq = (const float*)d_in[1];
  const float* bq = (const float*)d_in[2];
  const float* Wk = (const float*)d_in[3];
  const float* bk = (const float*)d_in[4];
  const float* Wv = (const float*)d_in[5];
  const float* bv = (const float*)d_in[6];
  const float* f  = (const float*)d_in[7];
  float* out = (float*)d_out;

  // ws layout (bf16 shorts):
  //   xb:  65536*512            = 33,554,432   (67 MB)
  //   wb:  3 * 512*512          =    786,432   (1.5 MB)
  //   Qb/Kb/Vb: 3 * 33,554,432               (201 MB)
  ushort_t* xb = (ushort_t*)d_ws;
  ushort_t* wb = xb + 33554432u;
  ushort_t* Qb = wb + 786432u;
  ushort_t* Kb = Qb + 33554432u;
  ushort_t* Vb = Kb + 33554432u;

  cast_f32_bf16<<<33554432 / 4 / 256, 256, 0, stream>>>(x, xb, 33554432 / 4);
  cast_f32_bf16<<<262144 / 4 / 256, 256, 0, stream>>>(Wq, wb, 262144 / 4);
  cast_f32_bf16<<<262144 / 4 / 256, 256, 0, stream>>>(Wk, wb + 262144u, 262144 / 4);
  cast_f32_bf16<<<262144 / 4 / 256, 256, 0, stream>>>(Wv, wb + 524288u, 262144 / 4);

  dim3 g1(4, 512, 3);  // N-blocks, M-blocks, {q,k,v}
  gemm_qkv<<<g1, 256, 0, stream>>>(xb, wb, bq, wb + 262144u, bk,
                                   wb + 524288u, bv, Qb, Kb, Vb);

  dim3 g2(64, 32);  // (a, b)
  attn_bc<<<g2, 256, 0, stream>>>(Qb, Kb, Vb, f, out);
}